// Round 1
// baseline (2539.450 us; speedup 1.0000x reference)
//
#include <hip/hip_runtime.h>
#include <cstdint>

typedef short  short8  __attribute__((ext_vector_type(8)));
typedef unsigned short ushort8 __attribute__((ext_vector_type(8)));
typedef float  f32x4   __attribute__((ext_vector_type(4)));

#define NPOS 2500
#define NA   22500
#define TOPN 6000
#define NKEEP 300

__device__ __forceinline__ unsigned short f2bf(float f) {
  unsigned u = __float_as_uint(f);
  return (unsigned short)((u + 0x7FFFu + ((u >> 16) & 1u)) >> 16);
}

// ---------------- K1: patchify conv as GEMM  M=2500 N=512 K=768 ----------------
__global__ __launch_bounds__(256) void k1_patch(const float* __restrict__ img,
    const float* __restrict__ wf, const float* __restrict__ bf,
    float* __restrict__ feat, float* __restrict__ feat_t)
{
  __shared__ float As[64][64];   // [k][m]
  __shared__ float Bs[64][64];   // [k][n]
  int tid = threadIdx.x;
  int tx = tid & 15, ty = tid >> 4;
  int m0 = blockIdx.x * 64, n0 = blockIdx.y * 64;
  float acc[4][4];
#pragma unroll
  for (int i = 0; i < 4; ++i)
#pragma unroll
    for (int j = 0; j < 4; ++j) acc[i][j] = 0.f;

  for (int k0 = 0; k0 < 768; k0 += 64) {
#pragma unroll
    for (int i = 0; i < 16; ++i) {
      int flat = i * 256 + tid;
      int k = flat >> 6, m = flat & 63;
      int gm = m0 + m;
      float v = 0.f;
      if (gm < NPOS) {
        int kk = k0 + k;
        int ci = kk >> 8, r = (kk >> 4) & 15, cc = kk & 15;
        int y = gm / 50, x = gm - y * 50;
        v = img[ci * 640000 + (y * 16 + r) * 800 + (x * 16 + cc)];
      }
      As[k][m] = v;
    }
#pragma unroll
    for (int i = 0; i < 16; ++i) {
      int flat = i * 256 + tid;
      int k = flat >> 6, n = flat & 63;
      Bs[k][n] = wf[(n0 + n) * 768 + (k0 + k)];
    }
    __syncthreads();
#pragma unroll 8
    for (int k = 0; k < 64; ++k) {
      float4 a = *(const float4*)&As[k][ty * 4];
      float4 b = *(const float4*)&Bs[k][tx * 4];
      float av[4] = {a.x, a.y, a.z, a.w};
      float bv[4] = {b.x, b.y, b.z, b.w};
#pragma unroll
      for (int i = 0; i < 4; ++i)
#pragma unroll
        for (int j = 0; j < 4; ++j) acc[i][j] += av[i] * bv[j];
    }
    __syncthreads();
  }
#pragma unroll
  for (int i = 0; i < 4; ++i) {
    int m = m0 + ty * 4 + i;
    if (m >= NPOS) continue;
#pragma unroll
    for (int j = 0; j < 4; ++j) {
      int n = n0 + tx * 4 + j;
      float v = acc[i][j] + bf[n];
      feat[n * NPOS + m] = v;      // [c][y][x]
      feat_t[m * 512 + n] = v;     // [y][x][c]
    }
  }
}

// ---------------- K2: RPN 3x3 conv as GEMM  M=2500 N=512 K=4608, ReLU ----------------
__global__ __launch_bounds__(256) void k2_rpn(const float* __restrict__ feat,
    const float* __restrict__ wr, const float* __restrict__ br,
    float* __restrict__ h_t)
{
  __shared__ float As[64][64];
  __shared__ float Bs[64][64];
  int tid = threadIdx.x;
  int tx = tid & 15, ty = tid >> 4;
  int m0 = blockIdx.x * 64, n0 = blockIdx.y * 64;
  float acc[4][4];
#pragma unroll
  for (int i = 0; i < 4; ++i)
#pragma unroll
    for (int j = 0; j < 4; ++j) acc[i][j] = 0.f;

  for (int k0 = 0; k0 < 4608; k0 += 64) {
#pragma unroll
    for (int i = 0; i < 16; ++i) {
      int flat = i * 256 + tid;
      int k = flat >> 6, m = flat & 63;
      int gm = m0 + m;
      int kk = k0 + k;
      int c = kk / 9;
      int rem = kk - c * 9;
      int dy = rem / 3;
      int dx = rem - dy * 3;
      float v = 0.f;
      if (gm < NPOS) {
        int yy = gm / 50 + dy - 1;
        int xx = (gm - (gm / 50) * 50) + dx - 1;
        if (yy >= 0 && yy < 50 && xx >= 0 && xx < 50)
          v = feat[c * NPOS + yy * 50 + xx];
      }
      As[k][m] = v;
    }
#pragma unroll
    for (int i = 0; i < 16; ++i) {
      int flat = i * 256 + tid;
      int k = flat >> 6, n = flat & 63;
      Bs[k][n] = wr[(size_t)(n0 + n) * 4608 + (k0 + k)];
    }
    __syncthreads();
#pragma unroll 8
    for (int k = 0; k < 64; ++k) {
      float4 a = *(const float4*)&As[k][ty * 4];
      float4 b = *(const float4*)&Bs[k][tx * 4];
      float av[4] = {a.x, a.y, a.z, a.w};
      float bv[4] = {b.x, b.y, b.z, b.w};
#pragma unroll
      for (int i = 0; i < 4; ++i)
#pragma unroll
        for (int j = 0; j < 4; ++j) acc[i][j] += av[i] * bv[j];
    }
    __syncthreads();
  }
#pragma unroll
  for (int i = 0; i < 4; ++i) {
    int m = m0 + ty * 4 + i;
    if (m >= NPOS) continue;
#pragma unroll
    for (int j = 0; j < 4; ++j) {
      int n = n0 + tx * 4 + j;
      h_t[m * 512 + n] = fmaxf(acc[i][j] + br[n], 0.f);
    }
  }
}

// ---------------- K3: score/delta 1x1 + softmax + anchor decode + sort keys ----------------
__global__ __launch_bounds__(64) void k3_head(const float* __restrict__ h_t,
    const float* __restrict__ w_score, const float* __restrict__ b_score,
    const float* __restrict__ w_delta, const float* __restrict__ b_delta,
    float4* __restrict__ boxes, unsigned long long* __restrict__ keys)
{
  __shared__ float4 hv4[128];
  __shared__ float outv[54];
  int p = blockIdx.x, tid = threadIdx.x;
  const float4* src = (const float4*)(h_t + (size_t)p * 512);
  hv4[tid] = src[tid];
  hv4[tid + 64] = src[tid + 64];
  __syncthreads();
  if (tid < 54) {
    const float* w; float bb;
    if (tid < 18) { w = w_score + tid * 512; bb = b_score[tid]; }
    else          { w = w_delta + (tid - 18) * 512; bb = b_delta[tid - 18]; }
    const float4* w4 = (const float4*)w;
    float s = 0.f;
#pragma unroll 4
    for (int q = 0; q < 128; ++q) {
      float4 a = hv4[q], b = w4[q];
      s += a.x * b.x + a.y * b.y + a.z * b.z + a.w * b.w;
    }
    outv[tid] = s + bb;
  }
  __syncthreads();
  if (tid < 9) {
    int k = tid;
    float s0 = outv[2 * k], s1 = outv[2 * k + 1];
    float mx = fmaxf(s0, s1);
    float e0 = expf(s0 - mx), e1 = expf(s1 - mx);
    float f = e1 / (e0 + e1);
    // anchors in double (matches numpy f64 -> f32 cast)
    double ratio = (k < 3) ? 0.5 : ((k < 6) ? 1.0 : 2.0);
    int si = k - (k / 3) * 3;
    double scale = (si == 0) ? 8.0 : ((si == 1) ? 16.0 : 32.0);
    double sq = sqrt(ratio);
    double wsd = 16.0 * scale / sq;
    double hsd = 16.0 * scale * sq;
    int y = p / 50, x = p - (p / 50) * 50;
    double cxd = ((double)x + 0.5) * 16.0;
    double cyd = ((double)y + 0.5) * 16.0;
    float ax1 = (float)(cxd - wsd / 2.0);
    float ay1 = (float)(cyd - hsd / 2.0);
    float ax2 = (float)(cxd + wsd / 2.0);
    float ay2 = (float)(cyd + hsd / 2.0);
    // decode (f32, mirrors reference)
    float aw = ax2 - ax1, ah = ay2 - ay1;
    float axc = ax1 + aw * 0.5f, ayc = ay1 + ah * 0.5f;
    float d0 = outv[18 + 4 * k], d1 = outv[18 + 4 * k + 1];
    float d2 = outv[18 + 4 * k + 2], d3 = outv[18 + 4 * k + 3];
    float cx = axc + d0 * aw, cy = ayc + d1 * ah;
    float bw = aw * expf(d2), bh = ah * expf(d3);
    float bx1 = fminf(fmaxf(cx - bw * 0.5f, 0.f), 800.f);
    float by1 = fminf(fmaxf(cy - bh * 0.5f, 0.f), 800.f);
    float bx2 = fminf(fmaxf(cx + bw * 0.5f, 0.f), 800.f);
    float by2 = fminf(fmaxf(cy + bh * 0.5f, 0.f), 800.f);
    int idx = p * 9 + k;
    boxes[idx] = make_float4(bx1, by1, bx2, by2);
    // fg > 0 always -> positive-float bits are order-preserving.
    keys[idx] = ((unsigned long long)__float_as_uint(f) << 32)
              | (unsigned long long)(0xFFFFFFFFu - (unsigned)idx);
  }
}

// ---------------- K4: exact top-6000 by rank (matches lax.top_k tie rules) ----------------
__global__ __launch_bounds__(256) void k4_rank(const unsigned long long* __restrict__ keys,
    const float4* __restrict__ boxes, float4* __restrict__ cand, float* __restrict__ areas)
{
  __shared__ unsigned long long tile[2048];
  int i = blockIdx.x * 256 + threadIdx.x;
  unsigned long long my = (i < NA) ? keys[i] : 0ull;
  int rank = 0;
  for (int t0 = 0; t0 < 22528; t0 += 2048) {
#pragma unroll
    for (int j = 0; j < 8; ++j) {
      int idx = t0 + j * 256 + threadIdx.x;
      tile[j * 256 + threadIdx.x] = (idx < NA) ? keys[idx] : 0ull;
    }
    __syncthreads();
#pragma unroll 8
    for (int j = 0; j < 2048; ++j) rank += (tile[j] > my) ? 1 : 0;
    __syncthreads();
  }
  if (i < NA && rank < TOPN) {
    float4 b = boxes[i];
    cand[rank] = b;
    areas[rank] = (b.z - b.x) * (b.w - b.y);
  }
}

// ---------------- K5: IoU > 0.7 bit matrix (row i, bits j>i) ----------------
__global__ __launch_bounds__(256) void k5_iou(const float4* __restrict__ cand,
    const float* __restrict__ areas, unsigned long long* __restrict__ rowbuf)
{
  int i = blockIdx.x;
  int j = blockIdx.y * 256 + threadIdx.x;
  float4 bi = cand[i];
  float ai = areas[i];
  bool bit = false;
  if (j > i && j < TOPN) {
    float4 bj = cand[j];
    float lx = fmaxf(bi.x, bj.x), ly = fmaxf(bi.y, bj.y);
    float rx = fminf(bi.z, bj.z), ry = fminf(bi.w, bj.w);
    float ww = fmaxf(rx - lx, 0.f), hh = fmaxf(ry - ly, 0.f);
    float inter = ww * hh;
    float iou = inter / (ai + areas[j] - inter + 1e-9f);
    bit = iou > 0.7f;
  }
  unsigned long long m = __ballot(bit);
  if ((threadIdx.x & 63) == 0)
    rowbuf[(size_t)i * 96 + blockIdx.y * 4 + (threadIdx.x >> 6)] = m;
}

// ---------------- K6: sequential greedy NMS scan + keep->rois (single block) ----------------
__global__ __launch_bounds__(256) void k6_scan(const unsigned long long* __restrict__ rowbuf,
    const float4* __restrict__ cand, float4* __restrict__ rois)
{
  __shared__ unsigned long long stage[64][96];
  __shared__ unsigned long long sup[96];
  __shared__ int prefU[94], prefS[94];
  __shared__ int totU;
  int tid = threadIdx.x;
  if (tid < 96) sup[tid] = 0ull;
  __syncthreads();
  for (int c = 0; c < 94; ++c) {
    for (int t = tid; t < 6144; t += 256) {
      int b = t / 96, w = t - (t / 96) * 96;
      int row = c * 64 + b;
      stage[b][w] = (row < TOPN) ? rowbuf[(size_t)row * 96 + w] : 0ull;
    }
    __syncthreads();
    unsigned long long valid = (c == 93) ? ((1ull << 48) - 1ull) : ~0ull;
    unsigned long long sup_c = sup[c];
    unsigned long long live0 = ~sup_c & valid;
    unsigned long long rw = stage[tid & 63][c];   // lane l: word c of row c*64+l
    unsigned long long live = live0, keep = 0ull;
    while (live) {
      int b = __builtin_ctzll(live);
      keep |= 1ull << b;
      unsigned long long rb = __shfl(rw, b);      // suppression bits from kept row
      live &= ~rb;
      live &= ~(1ull << b);
    }
    __syncthreads();
    if (tid == 0) sup[c] = sup_c | (live0 & ~keep);
    for (int w = c + 1 + tid; w < 94; w += 256) {
      unsigned long long a = sup[w];
      unsigned long long kk = keep;
      while (kk) {
        int b = __builtin_ctzll(kk);
        kk &= kk - 1;
        a |= stage[b][w];
      }
      sup[w] = a;
    }
    __syncthreads();
  }
  if (tid == 0) {
    int u = 0, s = 0;
    for (int w = 0; w < 94; ++w) {
      prefU[w] = u; prefS[w] = s;
      unsigned long long valid = (w == 93) ? ((1ull << 48) - 1ull) : ~0ull;
      unsigned long long sw = sup[w];
      u += __popcll(~sw & valid);
      s += __popcll(sw & valid);
    }
    totU = u;
  }
  __syncthreads();
  // keep order: unsuppressed in index order (= score desc), then suppressed ascending (-inf ties)
  for (int i = tid; i < TOPN; i += 256) {
    int w = i >> 6, b = i & 63;
    unsigned long long sw = sup[w];
    unsigned long long below = (b == 0) ? 0ull : (~0ull >> (64 - b));
    bool s = (sw >> b) & 1ull;
    int pos = s ? (totU + prefS[w] + __popcll(sw & below))
                : (prefU[w] + __popcll(~sw & below));
    if (pos < NKEEP) rois[pos] = cand[i];
  }
}

// ---------------- K7: roi_align (P=7, SAMP=2) -> pool in bf16 [roi][c*49+py*7+px] ----------------
__global__ __launch_bounds__(256) void k7_roi(const float4* __restrict__ rois,
    const float* __restrict__ feat_t, unsigned short* __restrict__ pool_bf)
{
  int r = blockIdx.x;
  int py = blockIdx.y / 7, px = blockIdx.y - (blockIdx.y / 7) * 7;
  int c = threadIdx.x;
  float4 box = rois[r];
  float x1 = box.x * 0.0625f, y1 = box.y * 0.0625f;
  float x2 = box.z * 0.0625f, y2 = box.w * 0.0625f;
  float acc0 = 0.f, acc1 = 0.f;
#pragma unroll
  for (int sy = 0; sy < 2; ++sy) {
#pragma unroll
    for (int sx = 0; sx < 2; ++sx) {
      float offx = ((float)(2 * px + sx) + 0.5f) * 0.5f;
      float offy = ((float)(2 * py + sy) + 0.5f) * 0.5f;
      float xs = x1 + (offx * (x2 - x1)) / 7.f;
      float ys = y1 + (offy * (y2 - y1)) / 7.f;
      float x0f = floorf(xs), y0f = floorf(ys);
      float lx = xs - x0f, ly = ys - y0f;
      int x0i = (int)fminf(fmaxf(x0f, 0.f), 49.f);
      int x1i = (int)fminf(fmaxf(x0f + 1.f, 0.f), 49.f);
      int y0i = (int)fminf(fmaxf(y0f, 0.f), 49.f);
      int y1i = (int)fminf(fmaxf(y0f + 1.f, 0.f), 49.f);
      const float* f00 = feat_t + (size_t)(y0i * 50 + x0i) * 512;
      const float* f01 = feat_t + (size_t)(y0i * 50 + x1i) * 512;
      const float* f10 = feat_t + (size_t)(y1i * 50 + x0i) * 512;
      const float* f11 = feat_t + (size_t)(y1i * 50 + x1i) * 512;
      float w00 = (1.f - ly) * (1.f - lx), w01 = (1.f - ly) * lx;
      float w10 = ly * (1.f - lx),          w11 = ly * lx;
      acc0 += w00 * f00[c] + w01 * f01[c] + w10 * f10[c] + w11 * f11[c];
      acc1 += w00 * f00[c + 256] + w01 * f01[c + 256] + w10 * f10[c + 256] + w11 * f11[c + 256];
    }
  }
  pool_bf[(size_t)r * 25088 + c * 49 + py * 7 + px] = f2bf(acc0 * 0.25f);
  pool_bf[(size_t)r * 25088 + (c + 256) * 49 + py * 7 + px] = f2bf(acc1 * 0.25f);
}

// ---------------- K8: fc7 GEMM  A(320x25088 bf16) x W^T(4096x25088 f32->bf16), split-K partials ----------------
__global__ __launch_bounds__(512) void k8_gemm(const unsigned short* __restrict__ A,
    const float* __restrict__ W, float* __restrict__ partial, int klen)
{
  // grouped LDS layouts [g][row][8] -> conflict-free ds_read_b128 fragments
  __shared__ __align__(16) unsigned short As[8 * 320 * 8];  // 40KB
  __shared__ __align__(16) unsigned short Bs[8 * 128 * 8];  // 16KB
  int tid = threadIdx.x;
  int lane = tid & 63, wv = tid >> 6;
  int wm = wv & 1, wn = wv >> 1;      // wave tile: rows wm*160+, cols wn*32+
  int n0 = blockIdx.x * 128;
  int kbase = blockIdx.y * klen;
  f32x4 acc[10][2];
#pragma unroll
  for (int i = 0; i < 10; ++i)
#pragma unroll
    for (int j = 0; j < 2; ++j) acc[i][j] = (f32x4){0.f, 0.f, 0.f, 0.f};

  for (int kt = 0; kt < klen; kt += 64) {
    int k0 = kbase + kt;
    // stage A: 2560 x 16B slots, linear in o = g*320+m
#pragma unroll
    for (int j = 0; j < 5; ++j) {
      int o = j * 512 + tid;
      int g = o / 320, m = o - g * 320;
      ((ushort8*)As)[o] = *(const ushort8*)(A + (size_t)m * 25088 + k0 + g * 8);
    }
    // stage B: f32 -> bf16 on the fly
#pragma unroll
    for (int j = 0; j < 4; ++j) {
      int fq = j * 512 + tid;
      int n = fq >> 4, kq = fq & 15;
      float4 v = *(const float4*)(W + (size_t)(n0 + n) * 25088 + k0 + kq * 4);
      unsigned long long pk = (unsigned long long)f2bf(v.x)
        | ((unsigned long long)f2bf(v.y) << 16)
        | ((unsigned long long)f2bf(v.z) << 32)
        | ((unsigned long long)f2bf(v.w) << 48);
      int g = kq >> 1;
      *(unsigned long long*)&Bs[(g * 128 + n) * 8 + (kq & 1) * 4] = pk;
    }
    __syncthreads();
#pragma unroll
    for (int kk = 0; kk < 2; ++kk) {
      int g = kk * 4 + (lane >> 4);
      short8 b0 = ((const short8*)Bs)[g * 128 + wn * 32 + (lane & 15)];
      short8 b1 = ((const short8*)Bs)[g * 128 + wn * 32 + 16 + (lane & 15)];
#pragma unroll
      for (int fm = 0; fm < 10; ++fm) {
        short8 a = ((const short8*)As)[g * 320 + wm * 160 + fm * 16 + (lane & 15)];
        acc[fm][0] = __builtin_amdgcn_mfma_f32_16x16x32_bf16(a, b0, acc[fm][0], 0, 0, 0);
        acc[fm][1] = __builtin_amdgcn_mfma_f32_16x16x32_bf16(a, b1, acc[fm][1], 0, 0, 0);
      }
    }
    __syncthreads();
  }
  float* P = partial + (size_t)(blockIdx.y * 32 + blockIdx.x) * (320 * 128);
#pragma unroll
  for (int fm = 0; fm < 10; ++fm)
#pragma unroll
    for (int fn = 0; fn < 2; ++fn)
#pragma unroll
      for (int r = 0; r < 4; ++r) {
        int m = wm * 160 + fm * 16 + (lane >> 4) * 4 + r;
        int n = wn * 32 + fn * 16 + (lane & 15);
        P[m * 128 + n] = acc[fm][fn][r];
      }
}

__global__ __launch_bounds__(256) void k8_reduce(const float* __restrict__ partial,
    const float* __restrict__ bias, float* __restrict__ fc7, int KS)
{
  int idx = blockIdx.x * 256 + threadIdx.x;
  if (idx >= 300 * 4096) return;
  int m = idx >> 12, n = idx & 4095;
  int nt = n >> 7, nn = n & 127;
  float s = 0.f;
  for (int ks = 0; ks < KS; ++ks)
    s += partial[((size_t)(ks * 32 + nt) * 320 + m) * 128 + nn];
  s += bias[n];
  fc7[idx] = fmaxf(s, 0.f);
}

// ---------------- K9: cls/reg heads (f32) -> output ----------------
__global__ __launch_bounds__(128) void k9_head(const float* __restrict__ fc7,
    const float* __restrict__ wc, const float* __restrict__ bc,
    const float* __restrict__ wr, const float* __restrict__ br,
    float* __restrict__ out)
{
  __shared__ float4 fv4[1024];
  int m = blockIdx.x, tid = threadIdx.x;
  const float4* src = (const float4*)(fc7 + (size_t)m * 4096);
  for (int i = tid; i < 1024; i += 128) fv4[i] = src[i];
  __syncthreads();
  if (tid < 105) {
    const float* w; float b;
    if (tid < 21) { w = wc + tid * 4096; b = bc[tid]; }
    else          { w = wr + (tid - 21) * 4096; b = br[tid - 21]; }
    const float4* w4 = (const float4*)w;
    float s = 0.f;
#pragma unroll 4
    for (int q = 0; q < 1024; ++q) {
      float4 a = fv4[q], ww = w4[q];
      s += a.x * ww.x + a.y * ww.y + a.z * ww.z + a.w * ww.w;
    }
    s += b;
    if (tid < 21) out[m * 21 + tid] = s;
    else          out[6300 + m * 84 + (tid - 21)] = s;
  }
}

extern "C" void kernel_launch(void* const* d_in, const int* in_sizes, int n_in,
                              void* d_out, int out_size, void* d_ws, size_t ws_size,
                              hipStream_t stream)
{
  (void)in_sizes; (void)n_in; (void)out_size;
  const float* img    = (const float*)d_in[0];
  const float* w_feat = (const float*)d_in[1];
  const float* b_feat = (const float*)d_in[2];
  const float* w_rpn  = (const float*)d_in[3];
  const float* b_rpn  = (const float*)d_in[4];
  const float* w_score= (const float*)d_in[5];
  const float* b_score= (const float*)d_in[6];
  const float* w_delta= (const float*)d_in[7];
  const float* b_delta= (const float*)d_in[8];
  const float* w_fc7  = (const float*)d_in[9];
  const float* b_fc7  = (const float*)d_in[10];
  const float* w_cls  = (const float*)d_in[11];
  const float* b_cls  = (const float*)d_in[12];
  const float* w_reg  = (const float*)d_in[13];
  const float* b_reg  = (const float*)d_in[14];
  float* out = (float*)d_out;

  char* ws = (char*)d_ws;
  size_t off = 0;
  auto alloc = [&](size_t bytes) -> void* {
    void* p = ws + off;
    off = (off + bytes + 511) & ~(size_t)511;
    return p;
  };
  float* feat    = (float*)alloc(5120000);
  float* feat_t  = (float*)alloc(5120000);
  float* h_t     = (float*)alloc(5120000);
  float4* boxes  = (float4*)alloc((size_t)NA * 16);
  unsigned long long* keys = (unsigned long long*)alloc((size_t)NA * 8);
  float4* cand   = (float4*)alloc((size_t)TOPN * 16);
  float* areas   = (float*)alloc((size_t)TOPN * 4);
  unsigned long long* rowbuf = (unsigned long long*)alloc((size_t)TOPN * 96 * 8);
  float4* rois   = (float4*)alloc(NKEEP * 16);
  unsigned short* pool_bf = (unsigned short*)alloc((size_t)320 * 25088 * 2);
  float* fc7     = (float*)alloc((size_t)300 * 4096 * 4);
  int KS = 8;
  while (KS > 1 && off + (size_t)KS * 32 * 320 * 128 * 4 > ws_size) KS >>= 1;
  float* partial = (float*)alloc((size_t)KS * 32 * 320 * 128 * 4);
  int klen = 25088 / KS;

  k1_patch<<<dim3(40, 8), 256, 0, stream>>>(img, w_feat, b_feat, feat, feat_t);
  k2_rpn  <<<dim3(40, 8), 256, 0, stream>>>(feat, w_rpn, b_rpn, h_t);
  k3_head <<<2500, 64, 0, stream>>>(h_t, w_score, b_score, w_delta, b_delta, boxes, keys);
  k4_rank <<<88, 256, 0, stream>>>(keys, boxes, cand, areas);
  k5_iou  <<<dim3(6000, 24), 256, 0, stream>>>(cand, areas, rowbuf);
  k6_scan <<<1, 256, 0, stream>>>(rowbuf, cand, rois);
  hipMemsetAsync((void*)pool_bf, 0, (size_t)320 * 25088 * 2, stream);
  k7_roi  <<<dim3(300, 49), 256, 0, stream>>>(rois, feat_t, pool_bf);
  k8_gemm <<<dim3(32, KS), 512, 0, stream>>>(pool_bf, w_fc7, partial, klen);
  k8_reduce<<<(300 * 4096 + 255) / 256, 256, 0, stream>>>(partial, b_fc7, fc7, KS);
  k9_head <<<300, 128, 0, stream>>>(fc7, w_cls, b_cls, w_reg, b_reg, out);
}

// Round 2
// 1588.995 us; speedup vs baseline: 1.5981x; 1.5981x over previous
//
#include <hip/hip_runtime.h>
#include <cstdint>

typedef short  short8  __attribute__((ext_vector_type(8)));
typedef unsigned short ushort8 __attribute__((ext_vector_type(8)));
typedef float  f32x4   __attribute__((ext_vector_type(4)));

#define NPOS 2500
#define NA   22500
#define TOPN 6000
#define NKEEP 300

__device__ __forceinline__ unsigned short f2bf(float f) {
  unsigned u = __float_as_uint(f);
  return (unsigned short)((u + 0x7FFFu + ((u >> 16) & 1u)) >> 16);
}

// ---------------- K1: patchify conv as GEMM  M=2500 N=512 K=768 ----------------
__global__ __launch_bounds__(256) void k1_patch(const float* __restrict__ img,
    const float* __restrict__ wf, const float* __restrict__ bf,
    float* __restrict__ feat, float* __restrict__ feat_t)
{
  __shared__ float As[64][64];   // [k][m]
  __shared__ float Bs[64][64];   // [k][n]
  int tid = threadIdx.x;
  int tx = tid & 15, ty = tid >> 4;
  int m0 = blockIdx.x * 64, n0 = blockIdx.y * 64;
  float acc[4][4];
#pragma unroll
  for (int i = 0; i < 4; ++i)
#pragma unroll
    for (int j = 0; j < 4; ++j) acc[i][j] = 0.f;

  for (int k0 = 0; k0 < 768; k0 += 64) {
#pragma unroll
    for (int i = 0; i < 16; ++i) {
      int flat = i * 256 + tid;
      int k = flat >> 6, m = flat & 63;
      int gm = m0 + m;
      float v = 0.f;
      if (gm < NPOS) {
        int kk = k0 + k;
        int ci = kk >> 8, r = (kk >> 4) & 15, cc = kk & 15;
        int y = gm / 50, x = gm - y * 50;
        v = img[ci * 640000 + (y * 16 + r) * 800 + (x * 16 + cc)];
      }
      As[k][m] = v;
    }
#pragma unroll
    for (int i = 0; i < 16; ++i) {
      int flat = i * 256 + tid;
      int k = flat >> 6, n = flat & 63;
      Bs[k][n] = wf[(n0 + n) * 768 + (k0 + k)];
    }
    __syncthreads();
#pragma unroll 8
    for (int k = 0; k < 64; ++k) {
      float4 a = *(const float4*)&As[k][ty * 4];
      float4 b = *(const float4*)&Bs[k][tx * 4];
      float av[4] = {a.x, a.y, a.z, a.w};
      float bv[4] = {b.x, b.y, b.z, b.w};
#pragma unroll
      for (int i = 0; i < 4; ++i)
#pragma unroll
        for (int j = 0; j < 4; ++j) acc[i][j] += av[i] * bv[j];
    }
    __syncthreads();
  }
#pragma unroll
  for (int i = 0; i < 4; ++i) {
    int m = m0 + ty * 4 + i;
    if (m >= NPOS) continue;
#pragma unroll
    for (int j = 0; j < 4; ++j) {
      int n = n0 + tx * 4 + j;
      float v = acc[i][j] + bf[n];
      feat[n * NPOS + m] = v;      // [c][y][x]
      feat_t[m * 512 + n] = v;     // [y][x][c]
    }
  }
}

// ---------------- K2: RPN 3x3 conv as GEMM  M=2500 N=512 K=4608, ReLU ----------------
__global__ __launch_bounds__(256) void k2_rpn(const float* __restrict__ feat,
    const float* __restrict__ wr, const float* __restrict__ br,
    float* __restrict__ h_t)
{
  __shared__ float As[64][64];
  __shared__ float Bs[64][64];
  int tid = threadIdx.x;
  int tx = tid & 15, ty = tid >> 4;
  int m0 = blockIdx.x * 64, n0 = blockIdx.y * 64;
  float acc[4][4];
#pragma unroll
  for (int i = 0; i < 4; ++i)
#pragma unroll
    for (int j = 0; j < 4; ++j) acc[i][j] = 0.f;

  for (int k0 = 0; k0 < 4608; k0 += 64) {
#pragma unroll
    for (int i = 0; i < 16; ++i) {
      int flat = i * 256 + tid;
      int k = flat >> 6, m = flat & 63;
      int gm = m0 + m;
      int kk = k0 + k;
      int c = kk / 9;
      int rem = kk - c * 9;
      int dy = rem / 3;
      int dx = rem - dy * 3;
      float v = 0.f;
      if (gm < NPOS) {
        int yy = gm / 50 + dy - 1;
        int xx = (gm - (gm / 50) * 50) + dx - 1;
        if (yy >= 0 && yy < 50 && xx >= 0 && xx < 50)
          v = feat[c * NPOS + yy * 50 + xx];
      }
      As[k][m] = v;
    }
#pragma unroll
    for (int i = 0; i < 16; ++i) {
      int flat = i * 256 + tid;
      int k = flat >> 6, n = flat & 63;
      Bs[k][n] = wr[(size_t)(n0 + n) * 4608 + (k0 + k)];
    }
    __syncthreads();
#pragma unroll 8
    for (int k = 0; k < 64; ++k) {
      float4 a = *(const float4*)&As[k][ty * 4];
      float4 b = *(const float4*)&Bs[k][tx * 4];
      float av[4] = {a.x, a.y, a.z, a.w};
      float bv[4] = {b.x, b.y, b.z, b.w};
#pragma unroll
      for (int i = 0; i < 4; ++i)
#pragma unroll
        for (int j = 0; j < 4; ++j) acc[i][j] += av[i] * bv[j];
    }
    __syncthreads();
  }
#pragma unroll
  for (int i = 0; i < 4; ++i) {
    int m = m0 + ty * 4 + i;
    if (m >= NPOS) continue;
#pragma unroll
    for (int j = 0; j < 4; ++j) {
      int n = n0 + tx * 4 + j;
      h_t[m * 512 + n] = fmaxf(acc[i][j] + br[n], 0.f);
    }
  }
}

// ---------------- K3: score/delta 1x1 + softmax + anchor decode + sort keys ----------------
__global__ __launch_bounds__(64) void k3_head(const float* __restrict__ h_t,
    const float* __restrict__ w_score, const float* __restrict__ b_score,
    const float* __restrict__ w_delta, const float* __restrict__ b_delta,
    float4* __restrict__ boxes, unsigned long long* __restrict__ keys)
{
  __shared__ float4 hv4[128];
  __shared__ float outv[54];
  int p = blockIdx.x, tid = threadIdx.x;
  const float4* src = (const float4*)(h_t + (size_t)p * 512);
  hv4[tid] = src[tid];
  hv4[tid + 64] = src[tid + 64];
  __syncthreads();
  if (tid < 54) {
    const float* w; float bb;
    if (tid < 18) { w = w_score + tid * 512; bb = b_score[tid]; }
    else          { w = w_delta + (tid - 18) * 512; bb = b_delta[tid - 18]; }
    const float4* w4 = (const float4*)w;
    float s = 0.f;
#pragma unroll 4
    for (int q = 0; q < 128; ++q) {
      float4 a = hv4[q], b = w4[q];
      s += a.x * b.x + a.y * b.y + a.z * b.z + a.w * b.w;
    }
    outv[tid] = s + bb;
  }
  __syncthreads();
  if (tid < 9) {
    int k = tid;
    float s0 = outv[2 * k], s1 = outv[2 * k + 1];
    float mx = fmaxf(s0, s1);
    float e0 = expf(s0 - mx), e1 = expf(s1 - mx);
    float f = e1 / (e0 + e1);
    // anchors in double (matches numpy f64 -> f32 cast)
    double ratio = (k < 3) ? 0.5 : ((k < 6) ? 1.0 : 2.0);
    int si = k - (k / 3) * 3;
    double scale = (si == 0) ? 8.0 : ((si == 1) ? 16.0 : 32.0);
    double sq = sqrt(ratio);
    double wsd = 16.0 * scale / sq;
    double hsd = 16.0 * scale * sq;
    int y = p / 50, x = p - (p / 50) * 50;
    double cxd = ((double)x + 0.5) * 16.0;
    double cyd = ((double)y + 0.5) * 16.0;
    float ax1 = (float)(cxd - wsd / 2.0);
    float ay1 = (float)(cyd - hsd / 2.0);
    float ax2 = (float)(cxd + wsd / 2.0);
    float ay2 = (float)(cyd + hsd / 2.0);
    // decode (f32, mirrors reference)
    float aw = ax2 - ax1, ah = ay2 - ay1;
    float axc = ax1 + aw * 0.5f, ayc = ay1 + ah * 0.5f;
    float d0 = outv[18 + 4 * k], d1 = outv[18 + 4 * k + 1];
    float d2 = outv[18 + 4 * k + 2], d3 = outv[18 + 4 * k + 3];
    float cx = axc + d0 * aw, cy = ayc + d1 * ah;
    float bw = aw * expf(d2), bh = ah * expf(d3);
    float bx1 = fminf(fmaxf(cx - bw * 0.5f, 0.f), 800.f);
    float by1 = fminf(fmaxf(cy - bh * 0.5f, 0.f), 800.f);
    float bx2 = fminf(fmaxf(cx + bw * 0.5f, 0.f), 800.f);
    float by2 = fminf(fmaxf(cy + bh * 0.5f, 0.f), 800.f);
    int idx = p * 9 + k;
    boxes[idx] = make_float4(bx1, by1, bx2, by2);
    // fg > 0 always -> positive-float bits are order-preserving.
    keys[idx] = ((unsigned long long)__float_as_uint(f) << 32)
              | (unsigned long long)(0xFFFFFFFFu - (unsigned)idx);
  }
}

// ---------------- K4: exact top-6000 by rank (matches lax.top_k tie rules) ----------------
__global__ __launch_bounds__(256) void k4_rank(const unsigned long long* __restrict__ keys,
    const float4* __restrict__ boxes, float4* __restrict__ cand, float* __restrict__ areas)
{
  __shared__ unsigned long long tile[2048];
  int i = blockIdx.x * 256 + threadIdx.x;
  unsigned long long my = (i < NA) ? keys[i] : 0ull;
  int rank = 0;
  for (int t0 = 0; t0 < 22528; t0 += 2048) {
#pragma unroll
    for (int j = 0; j < 8; ++j) {
      int idx = t0 + j * 256 + threadIdx.x;
      tile[j * 256 + threadIdx.x] = (idx < NA) ? keys[idx] : 0ull;
    }
    __syncthreads();
#pragma unroll 8
    for (int j = 0; j < 2048; ++j) rank += (tile[j] > my) ? 1 : 0;
    __syncthreads();
  }
  if (i < NA && rank < TOPN) {
    float4 b = boxes[i];
    cand[rank] = b;
    areas[rank] = (b.z - b.x) * (b.w - b.y);
  }
}

// ---------------- K5: IoU > 0.7 bit matrix; one thread computes one 64-bit word ----------------
__global__ __launch_bounds__(256) void k5_iou(const float4* __restrict__ cand,
    const float* __restrict__ areas, unsigned long long* __restrict__ rowbuf)
{
  __shared__ float4 bj[64];
  __shared__ float aj[64];
  int jw = blockIdx.x;                       // word index 0..93
  int i = blockIdx.y * 256 + threadIdx.x;    // row
  if (threadIdx.x < 64) {
    int j = jw * 64 + threadIdx.x;
    bj[threadIdx.x] = (j < TOPN) ? cand[j] : make_float4(0.f, 0.f, 0.f, 0.f);
    aj[threadIdx.x] = (j < TOPN) ? areas[j] : 0.f;
  }
  __syncthreads();
  if (i >= TOPN) return;
  unsigned long long word = 0ull;
  if (jw * 64 + 63 > i) {
    float4 bi = cand[i];
    float ai = areas[i];
#pragma unroll 8
    for (int b = 0; b < 64; ++b) {
      float4 bb = bj[b];
      float lx = fmaxf(bi.x, bb.x), ly = fmaxf(bi.y, bb.y);
      float rx = fminf(bi.z, bb.z), ry = fminf(bi.w, bb.w);
      float ww = fmaxf(rx - lx, 0.f), hh = fmaxf(ry - ly, 0.f);
      float inter = ww * hh;
      float iou = inter / (ai + aj[b] - inter + 1e-9f);
      int j = jw * 64 + b;
      if (iou > 0.7f && j > i && j < TOPN) word |= 1ull << b;
    }
  }
  rowbuf[(size_t)i * 96 + jw] = word;
}

// ---------------- K6: greedy NMS scan, prefetched + early-exit (single block) ----------------
__global__ __launch_bounds__(256) void k6_scan(const unsigned long long* __restrict__ rowbuf,
    const float4* __restrict__ cand, float4* __restrict__ rois)
{
  __shared__ unsigned long long stage[64 * 97];   // [b][w], padded stride 97
  __shared__ unsigned long long sup[94];
  __shared__ int prefS[94];
  __shared__ int baseU_sh;
  int tid = threadIdx.x;
  if (tid < 94) sup[tid] = 0ull;
  if (tid == 0) baseU_sh = 0;

  // prefetch chunk 0 into registers
  unsigned long long pre[24];
#pragma unroll
  for (int j = 0; j < 24; ++j) {
    int o = j * 256 + tid;
    int b = o / 94, w = o - b * 94;
    pre[j] = (o < 6016) ? rowbuf[(size_t)b * 96 + w] : 0ull;
  }
  __syncthreads();

  for (int c = 0; c < 94; ++c) {
    // commit prefetched chunk to LDS
#pragma unroll
    for (int j = 0; j < 24; ++j) {
      int o = j * 256 + tid;
      int b = o / 94, w = o - b * 94;
      if (o < 6016) stage[b * 97 + w] = pre[j];
    }
    __syncthreads();
    // issue next chunk's loads; latency hides under the serial scan below
    if (c + 1 < 94) {
#pragma unroll
      for (int j = 0; j < 24; ++j) {
        int o = j * 256 + tid;
        int b = o / 94, w = o - b * 94;
        pre[j] = (o < 6016) ? rowbuf[((size_t)(c + 1) * 64 + b) * 96 + w] : 0ull;
      }
    }
    // serial greedy scan within chunk (all waves compute identically)
    unsigned long long valid = (c == 93) ? ((1ull << 48) - 1ull) : ~0ull;
    unsigned long long sup_c = sup[c];
    unsigned long long live0 = ~sup_c & valid;
    unsigned long long rw = stage[(tid & 63) * 97 + c];
    unsigned long long live = live0, keep = 0ull;
    while (live) {
      int b = __builtin_ctzll(live);
      keep |= 1ull << b;
      unsigned long long rb = (unsigned long long)__shfl((long long)rw, b);
      live &= ~rb;
      live &= ~(1ull << b);
    }
    int baseU = baseU_sh;
    // write kept boxes straight to rois
    if (tid < 64 && ((keep >> tid) & 1ull)) {
      unsigned long long below = (tid == 0) ? 0ull : (keep & ((1ull << tid) - 1ull));
      int pos = baseU + __popcll(below);
      if (pos < NKEEP) rois[pos] = cand[c * 64 + tid];
    }
    __syncthreads();
    if (tid == 0) baseU_sh = baseU + __popcll(keep);
    if (tid == 64) sup[c] = sup_c | (live0 & ~keep);
    // forward suppression update (fixed-bound loop pipelines LDS reads)
    for (int w = c + 1 + tid; w < 94; w += 256) {
      unsigned long long a = sup[w];
#pragma unroll 16
      for (int b = 0; b < 64; ++b)
        if ((keep >> b) & 1ull) a |= stage[b * 97 + w];
      sup[w] = a;
    }
    __syncthreads();
    if (baseU_sh >= NKEEP) break;   // first 300 unsuppressed found: done
  }

  int totU = baseU_sh;
  if (totU < NKEEP) {
    // tail: suppressed entries in ascending index order (-inf ties in top_k)
    if (tid == 0) {
      int s = 0;
      for (int w = 0; w < 94; ++w) { prefS[w] = s; s += __popcll(sup[w]); }
    }
    __syncthreads();
    for (int i = tid; i < TOPN; i += 256) {
      int w = i >> 6, b = i & 63;
      unsigned long long sw = sup[w];
      if ((sw >> b) & 1ull) {
        unsigned long long below = (b == 0) ? 0ull : (sw & ((1ull << b) - 1ull));
        int pos = totU + prefS[w] + __popcll(below);
        if (pos < NKEEP) rois[pos] = cand[i];
      }
    }
  }
}

// ---------------- K7: roi_align (P=7, SAMP=2) -> pool in bf16 [roi][c*49+py*7+px] ----------------
__global__ __launch_bounds__(256) void k7_roi(const float4* __restrict__ rois,
    const float* __restrict__ feat_t, unsigned short* __restrict__ pool_bf)
{
  int r = blockIdx.x;
  int py = blockIdx.y / 7, px = blockIdx.y - (blockIdx.y / 7) * 7;
  int c = threadIdx.x;
  float4 box = rois[r];
  float x1 = box.x * 0.0625f, y1 = box.y * 0.0625f;
  float x2 = box.z * 0.0625f, y2 = box.w * 0.0625f;
  float acc0 = 0.f, acc1 = 0.f;
#pragma unroll
  for (int sy = 0; sy < 2; ++sy) {
#pragma unroll
    for (int sx = 0; sx < 2; ++sx) {
      float offx = ((float)(2 * px + sx) + 0.5f) * 0.5f;
      float offy = ((float)(2 * py + sy) + 0.5f) * 0.5f;
      float xs = x1 + (offx * (x2 - x1)) / 7.f;
      float ys = y1 + (offy * (y2 - y1)) / 7.f;
      float x0f = floorf(xs), y0f = floorf(ys);
      float lx = xs - x0f, ly = ys - y0f;
      int x0i = (int)fminf(fmaxf(x0f, 0.f), 49.f);
      int x1i = (int)fminf(fmaxf(x0f + 1.f, 0.f), 49.f);
      int y0i = (int)fminf(fmaxf(y0f, 0.f), 49.f);
      int y1i = (int)fminf(fmaxf(y0f + 1.f, 0.f), 49.f);
      const float* f00 = feat_t + (size_t)(y0i * 50 + x0i) * 512;
      const float* f01 = feat_t + (size_t)(y0i * 50 + x1i) * 512;
      const float* f10 = feat_t + (size_t)(y1i * 50 + x0i) * 512;
      const float* f11 = feat_t + (size_t)(y1i * 50 + x1i) * 512;
      float w00 = (1.f - ly) * (1.f - lx), w01 = (1.f - ly) * lx;
      float w10 = ly * (1.f - lx),          w11 = ly * lx;
      acc0 += w00 * f00[c] + w01 * f01[c] + w10 * f10[c] + w11 * f11[c];
      acc1 += w00 * f00[c + 256] + w01 * f01[c + 256] + w10 * f10[c + 256] + w11 * f11[c + 256];
    }
  }
  pool_bf[(size_t)r * 25088 + c * 49 + py * 7 + px] = f2bf(acc0 * 0.25f);
  pool_bf[(size_t)r * 25088 + (c + 256) * 49 + py * 7 + px] = f2bf(acc1 * 0.25f);
}

// ---------------- K8: fc7 GEMM  A(320x25088 bf16) x W^T(4096x25088 f32->bf16), split-K partials ----------------
__global__ __launch_bounds__(512) void k8_gemm(const unsigned short* __restrict__ A,
    const float* __restrict__ W, float* __restrict__ partial, int klen)
{
  // grouped LDS layouts [g][row][8] -> conflict-free ds_read_b128 fragments
  __shared__ __align__(16) unsigned short As[8 * 320 * 8];  // 40KB
  __shared__ __align__(16) unsigned short Bs[8 * 128 * 8];  // 16KB
  int tid = threadIdx.x;
  int lane = tid & 63, wv = tid >> 6;
  int wm = wv & 1, wn = wv >> 1;      // wave tile: rows wm*160+, cols wn*32+
  int n0 = blockIdx.x * 128;
  int kbase = blockIdx.y * klen;
  f32x4 acc[10][2];
#pragma unroll
  for (int i = 0; i < 10; ++i)
#pragma unroll
    for (int j = 0; j < 2; ++j) acc[i][j] = (f32x4){0.f, 0.f, 0.f, 0.f};

  for (int kt = 0; kt < klen; kt += 64) {
    int k0 = kbase + kt;
    // stage A: 2560 x 16B slots, linear in o = g*320+m
#pragma unroll
    for (int j = 0; j < 5; ++j) {
      int o = j * 512 + tid;
      int g = o / 320, m = o - g * 320;
      ((ushort8*)As)[o] = *(const ushort8*)(A + (size_t)m * 25088 + k0 + g * 8);
    }
    // stage B: f32 -> bf16 on the fly
#pragma unroll
    for (int j = 0; j < 4; ++j) {
      int fq = j * 512 + tid;
      int n = fq >> 4, kq = fq & 15;
      float4 v = *(const float4*)(W + (size_t)(n0 + n) * 25088 + k0 + kq * 4);
      unsigned long long pk = (unsigned long long)f2bf(v.x)
        | ((unsigned long long)f2bf(v.y) << 16)
        | ((unsigned long long)f2bf(v.z) << 32)
        | ((unsigned long long)f2bf(v.w) << 48);
      int g = kq >> 1;
      *(unsigned long long*)&Bs[(g * 128 + n) * 8 + (kq & 1) * 4] = pk;
    }
    __syncthreads();
#pragma unroll
    for (int kk = 0; kk < 2; ++kk) {
      int g = kk * 4 + (lane >> 4);
      short8 b0 = ((const short8*)Bs)[g * 128 + wn * 32 + (lane & 15)];
      short8 b1 = ((const short8*)Bs)[g * 128 + wn * 32 + 16 + (lane & 15)];
#pragma unroll
      for (int fm = 0; fm < 10; ++fm) {
        short8 a = ((const short8*)As)[g * 320 + wm * 160 + fm * 16 + (lane & 15)];
        acc[fm][0] = __builtin_amdgcn_mfma_f32_16x16x32_bf16(a, b0, acc[fm][0], 0, 0, 0);
        acc[fm][1] = __builtin_amdgcn_mfma_f32_16x16x32_bf16(a, b1, acc[fm][1], 0, 0, 0);
      }
    }
    __syncthreads();
  }
  float* P = partial + (size_t)(blockIdx.y * 32 + blockIdx.x) * (320 * 128);
#pragma unroll
  for (int fm = 0; fm < 10; ++fm)
#pragma unroll
    for (int fn = 0; fn < 2; ++fn)
#pragma unroll
      for (int r = 0; r < 4; ++r) {
        int m = wm * 160 + fm * 16 + (lane >> 4) * 4 + r;
        int n = wn * 32 + fn * 16 + (lane & 15);
        P[m * 128 + n] = acc[fm][fn][r];
      }
}

__global__ __launch_bounds__(256) void k8_reduce(const float* __restrict__ partial,
    const float* __restrict__ bias, float* __restrict__ fc7, int KS)
{
  int idx = blockIdx.x * 256 + threadIdx.x;
  if (idx >= 300 * 4096) return;
  int m = idx >> 12, n = idx & 4095;
  int nt = n >> 7, nn = n & 127;
  float s = 0.f;
  for (int ks = 0; ks < KS; ++ks)
    s += partial[((size_t)(ks * 32 + nt) * 320 + m) * 128 + nn];
  s += bias[n];
  fc7[idx] = fmaxf(s, 0.f);
}

// ---------------- K9: cls/reg heads (f32) -> output ----------------
__global__ __launch_bounds__(128) void k9_head(const float* __restrict__ fc7,
    const float* __restrict__ wc, const float* __restrict__ bc,
    const float* __restrict__ wr, const float* __restrict__ br,
    float* __restrict__ out)
{
  __shared__ float4 fv4[1024];
  int m = blockIdx.x, tid = threadIdx.x;
  const float4* src = (const float4*)(fc7 + (size_t)m * 4096);
  for (int i = tid; i < 1024; i += 128) fv4[i] = src[i];
  __syncthreads();
  if (tid < 105) {
    const float* w; float b;
    if (tid < 21) { w = wc + tid * 4096; b = bc[tid]; }
    else          { w = wr + (tid - 21) * 4096; b = br[tid - 21]; }
    const float4* w4 = (const float4*)w;
    float s = 0.f;
#pragma unroll 4
    for (int q = 0; q < 1024; ++q) {
      float4 a = fv4[q], ww = w4[q];
      s += a.x * ww.x + a.y * ww.y + a.z * ww.z + a.w * ww.w;
    }
    s += b;
    if (tid < 21) out[m * 21 + tid] = s;
    else          out[6300 + m * 84 + (tid - 21)] = s;
  }
}

extern "C" void kernel_launch(void* const* d_in, const int* in_sizes, int n_in,
                              void* d_out, int out_size, void* d_ws, size_t ws_size,
                              hipStream_t stream)
{
  (void)in_sizes; (void)n_in; (void)out_size;
  const float* img    = (const float*)d_in[0];
  const float* w_feat = (const float*)d_in[1];
  const float* b_feat = (const float*)d_in[2];
  const float* w_rpn  = (const float*)d_in[3];
  const float* b_rpn  = (const float*)d_in[4];
  const float* w_score= (const float*)d_in[5];
  const float* b_score= (const float*)d_in[6];
  const float* w_delta= (const float*)d_in[7];
  const float* b_delta= (const float*)d_in[8];
  const float* w_fc7  = (const float*)d_in[9];
  const float* b_fc7  = (const float*)d_in[10];
  const float* w_cls  = (const float*)d_in[11];
  const float* b_cls  = (const float*)d_in[12];
  const float* w_reg  = (const float*)d_in[13];
  const float* b_reg  = (const float*)d_in[14];
  float* out = (float*)d_out;

  char* ws = (char*)d_ws;
  size_t off = 0;
  auto alloc = [&](size_t bytes) -> void* {
    void* p = ws + off;
    off = (off + bytes + 511) & ~(size_t)511;
    return p;
  };
  float* feat    = (float*)alloc(5120000);
  float* feat_t  = (float*)alloc(5120000);
  float* h_t     = (float*)alloc(5120000);
  float4* boxes  = (float4*)alloc((size_t)NA * 16);
  unsigned long long* keys = (unsigned long long*)alloc((size_t)NA * 8);
  float4* cand   = (float4*)alloc((size_t)TOPN * 16);
  float* areas   = (float*)alloc((size_t)TOPN * 4);
  unsigned long long* rowbuf = (unsigned long long*)alloc((size_t)TOPN * 96 * 8);
  float4* rois   = (float4*)alloc(NKEEP * 16);
  unsigned short* pool_bf = (unsigned short*)alloc((size_t)320 * 25088 * 2);
  float* fc7     = (float*)alloc((size_t)300 * 4096 * 4);
  int KS = 8;
  while (KS > 1 && off + (size_t)KS * 32 * 320 * 128 * 4 > ws_size) KS >>= 1;
  float* partial = (float*)alloc((size_t)KS * 32 * 320 * 128 * 4);
  int klen = 25088 / KS;

  k1_patch<<<dim3(40, 8), 256, 0, stream>>>(img, w_feat, b_feat, feat, feat_t);
  k2_rpn  <<<dim3(40, 8), 256, 0, stream>>>(feat, w_rpn, b_rpn, h_t);
  k3_head <<<2500, 64, 0, stream>>>(h_t, w_score, b_score, w_delta, b_delta, boxes, keys);
  k4_rank <<<88, 256, 0, stream>>>(keys, boxes, cand, areas);
  k5_iou  <<<dim3(94, 24), 256, 0, stream>>>(cand, areas, rowbuf);
  k6_scan <<<1, 256, 0, stream>>>(rowbuf, cand, rois);
  hipMemsetAsync((void*)pool_bf, 0, (size_t)320 * 25088 * 2, stream);
  k7_roi  <<<dim3(300, 49), 256, 0, stream>>>(rois, feat_t, pool_bf);
  k8_gemm <<<dim3(32, KS), 512, 0, stream>>>(pool_bf, w_fc7, partial, klen);
  k8_reduce<<<(300 * 4096 + 255) / 256, 256, 0, stream>>>(partial, b_fc7, fc7, KS);
  k9_head <<<300, 128, 0, stream>>>(fc7, w_cls, b_cls, w_reg, b_reg, out);
}

// Round 3
// 884.554 us; speedup vs baseline: 2.8709x; 1.7964x over previous
//
#include <hip/hip_runtime.h>
#include <cstdint>

typedef short  short8  __attribute__((ext_vector_type(8)));
typedef unsigned short ushort8 __attribute__((ext_vector_type(8)));
typedef float  f32x4   __attribute__((ext_vector_type(4)));
typedef unsigned long long u64;

#define NPOS 2500
#define NA   22500
#define TOPN 6000
#define NKEEP 300
#define NBUCK 65536

__device__ __forceinline__ unsigned short f2bf(float f) {
  unsigned u = __float_as_uint(f);
  return (unsigned short)((u + 0x7FFFu + ((u >> 16) & 1u)) >> 16);
}

// ============ K1/K2: split-K f32 GEMM, BM=BN=128, BK=32, 8x8 acc ============
// MODE 0: A = img patchify gather (K=768),  Asrc = img
// MODE 1: A = feat 3x3 im2col gather (K=4608), Asrc = feat [c][pos]
template<int MODE>
__global__ __launch_bounds__(256) void kgemm_f32(const float* __restrict__ Asrc,
    const float* __restrict__ Bsrc, float* __restrict__ P, int klen, int K)
{
  __shared__ float As[32][128];
  __shared__ float Bs[32][132];   // pad->132: 16B-aligned rows, low write conflicts
  int tid = threadIdx.x;
  int tx = tid & 15, ty = tid >> 4;
  int mt = blockIdx.x, nt = blockIdx.y;
  int m0 = mt * 128, n0 = nt * 128;
  int kbase = blockIdx.z * klen;

  int m_loc = tid & 127;
  int krow = tid >> 7;            // 0/1
  int gm = m0 + m_loc;
  int y = gm / 50, x = gm - y * 50;
  bool mok = gm < NPOS;

  float acc[8][8] = {};

  for (int kt = 0; kt < klen; kt += 32) {
    int k0 = kbase + kt;
    // A staging: each thread fills k_loc = 2i+krow, fixed m_loc (coalesced in m)
#pragma unroll
    for (int i = 0; i < 16; ++i) {
      int k_loc = 2 * i + krow;
      int kk = k0 + k_loc;
      float v = 0.f;
      if constexpr (MODE == 0) {
        int ci = kk >> 8, r = (kk >> 4) & 15, cc = kk & 15;
        if (mok) v = Asrc[ci * 640000 + (y * 16 + r) * 800 + (x * 16 + cc)];
      } else {
        int c = kk / 9;
        int rem = kk - c * 9;
        int dy = rem / 3, dx = rem - (rem / 3) * 3;
        int yy = y + dy - 1, xx = x + dx - 1;
        if (mok && (unsigned)yy < 50u && (unsigned)xx < 50u)
          v = Asrc[c * NPOS + yy * 50 + xx];
      }
      As[k_loc][m_loc] = v;
    }
    // B staging: float4 along k (coalesced), scatter into k-major LDS
#pragma unroll
    for (int i = 0; i < 4; ++i) {
      int e = i * 256 + tid;
      int k4 = e & 7, n = e >> 3;
      float4 v = *(const float4*)(Bsrc + (size_t)(n0 + n) * K + k0 + k4 * 4);
      Bs[k4 * 4 + 0][n] = v.x;
      Bs[k4 * 4 + 1][n] = v.y;
      Bs[k4 * 4 + 2][n] = v.z;
      Bs[k4 * 4 + 3][n] = v.w;
    }
    __syncthreads();
#pragma unroll 8
    for (int k = 0; k < 32; ++k) {
      float4 a0 = *(const float4*)&As[k][ty * 8];
      float4 a1 = *(const float4*)&As[k][ty * 8 + 4];
      float4 b0 = *(const float4*)&Bs[k][tx * 8];
      float4 b1 = *(const float4*)&Bs[k][tx * 8 + 4];
      float av[8] = {a0.x, a0.y, a0.z, a0.w, a1.x, a1.y, a1.z, a1.w};
      float bv[8] = {b0.x, b0.y, b0.z, b0.w, b1.x, b1.y, b1.z, b1.w};
#pragma unroll
      for (int i2 = 0; i2 < 8; ++i2)
#pragma unroll
        for (int j2 = 0; j2 < 8; ++j2) acc[i2][j2] += av[i2] * bv[j2];
    }
    __syncthreads();
  }
  float* Pp = P + ((size_t)(blockIdx.z * 20 + mt) * 4 + nt) * 16384;
#pragma unroll
  for (int i = 0; i < 8; ++i) {
    float4 v0 = {acc[i][0], acc[i][1], acc[i][2], acc[i][3]};
    float4 v1 = {acc[i][4], acc[i][5], acc[i][6], acc[i][7]};
    *(float4*)&Pp[(ty * 8 + i) * 128 + tx * 8] = v0;
    *(float4*)&Pp[(ty * 8 + i) * 128 + tx * 8 + 4] = v1;
  }
}

__global__ __launch_bounds__(256) void kred1(const float* __restrict__ P,
    const float* __restrict__ bias, float* __restrict__ feat,
    float* __restrict__ feat_t, int KS)
{
  int idx = blockIdx.x * 256 + threadIdx.x;
  if (idx >= NPOS * 512) return;
  int m = idx >> 9, n = idx & 511;
  int mt = m >> 7, ml = m & 127, nt = n >> 7, nl = n & 127;
  float s = 0.f;
  for (int z = 0; z < KS; ++z)
    s += P[(((size_t)(z * 20 + mt) * 4 + nt) << 14) + ml * 128 + nl];
  s += bias[n];
  feat[n * NPOS + m] = s;
  feat_t[m * 512 + n] = s;
}

__global__ __launch_bounds__(256) void kred2(const float* __restrict__ P,
    const float* __restrict__ bias, float* __restrict__ h_t, int KS)
{
  int idx = blockIdx.x * 256 + threadIdx.x;
  if (idx >= NPOS * 512) return;
  int m = idx >> 9, n = idx & 511;
  int mt = m >> 7, ml = m & 127, nt = n >> 7, nl = n & 127;
  float s = 0.f;
  for (int z = 0; z < KS; ++z)
    s += P[(((size_t)(z * 20 + mt) * 4 + nt) << 14) + ml * 128 + nl];
  h_t[m * 512 + n] = fmaxf(s + bias[n], 0.f);
}

// ---------------- K3: score/delta 1x1 + softmax + anchor decode + sort keys ----------------
__global__ __launch_bounds__(64) void k3_head(const float* __restrict__ h_t,
    const float* __restrict__ w_score, const float* __restrict__ b_score,
    const float* __restrict__ w_delta, const float* __restrict__ b_delta,
    float4* __restrict__ boxes, u64* __restrict__ keys)
{
  __shared__ float4 hv4[128];
  __shared__ float outv[54];
  int p = blockIdx.x, tid = threadIdx.x;
  const float4* src = (const float4*)(h_t + (size_t)p * 512);
  hv4[tid] = src[tid];
  hv4[tid + 64] = src[tid + 64];
  __syncthreads();
  if (tid < 54) {
    const float* w; float bb;
    if (tid < 18) { w = w_score + tid * 512; bb = b_score[tid]; }
    else          { w = w_delta + (tid - 18) * 512; bb = b_delta[tid - 18]; }
    const float4* w4 = (const float4*)w;
    float s = 0.f;
#pragma unroll 4
    for (int q = 0; q < 128; ++q) {
      float4 a = hv4[q], b = w4[q];
      s += a.x * b.x + a.y * b.y + a.z * b.z + a.w * b.w;
    }
    outv[tid] = s + bb;
  }
  __syncthreads();
  if (tid < 9) {
    int k = tid;
    float s0 = outv[2 * k], s1 = outv[2 * k + 1];
    float mx = fmaxf(s0, s1);
    float e0 = expf(s0 - mx), e1 = expf(s1 - mx);
    float f = e1 / (e0 + e1);
    double ratio = (k < 3) ? 0.5 : ((k < 6) ? 1.0 : 2.0);
    int si = k - (k / 3) * 3;
    double scale = (si == 0) ? 8.0 : ((si == 1) ? 16.0 : 32.0);
    double sq = sqrt(ratio);
    double wsd = 16.0 * scale / sq;
    double hsd = 16.0 * scale * sq;
    int y = p / 50, x = p - (p / 50) * 50;
    double cxd = ((double)x + 0.5) * 16.0;
    double cyd = ((double)y + 0.5) * 16.0;
    float ax1 = (float)(cxd - wsd / 2.0);
    float ay1 = (float)(cyd - hsd / 2.0);
    float ax2 = (float)(cxd + wsd / 2.0);
    float ay2 = (float)(cyd + hsd / 2.0);
    float aw = ax2 - ax1, ah = ay2 - ay1;
    float axc = ax1 + aw * 0.5f, ayc = ay1 + ah * 0.5f;
    float d0 = outv[18 + 4 * k], d1 = outv[18 + 4 * k + 1];
    float d2 = outv[18 + 4 * k + 2], d3 = outv[18 + 4 * k + 3];
    float cx = axc + d0 * aw, cy = ayc + d1 * ah;
    float bw = aw * expf(d2), bh = ah * expf(d3);
    float bx1 = fminf(fmaxf(cx - bw * 0.5f, 0.f), 800.f);
    float by1 = fminf(fmaxf(cy - bh * 0.5f, 0.f), 800.f);
    float bx2 = fminf(fmaxf(cx + bw * 0.5f, 0.f), 800.f);
    float by2 = fminf(fmaxf(cy + bh * 0.5f, 0.f), 800.f);
    int idx = p * 9 + k;
    boxes[idx] = make_float4(bx1, by1, bx2, by2);
    keys[idx] = ((u64)__float_as_uint(f) << 32) | (u64)(0xFFFFFFFFu - (unsigned)idx);
  }
}

// ============ K4: exact top-6000 via bucket histogram select ============
__global__ __launch_bounds__(256) void k4_hist(const u64* __restrict__ keys,
    int* __restrict__ hist)
{
  int i = blockIdx.x * 256 + threadIdx.x;
  if (i < NA) atomicAdd(&hist[(unsigned)(keys[i] >> 46)], 1);
}

__global__ __launch_bounds__(1024) void k4_scan(const int* __restrict__ hist,
    int* __restrict__ off, int* __restrict__ cur)
{
  __shared__ int ps[1024];
  int t = threadIdx.x;
  int s = 0;
  for (int j = 0; j < 64; ++j) s += hist[t * 64 + j];
  int mysum = s;
  ps[t] = s;
  __syncthreads();
  for (int d = 1; d < 1024; d <<= 1) {
    int v = ps[t];
    int u = (t >= d) ? ps[t - d] : 0;
    __syncthreads();
    ps[t] = v + u;
    __syncthreads();
  }
  int base = ps[t] - mysum;   // exclusive prefix of this thread's 64-chunk
  for (int j = 0; j < 64; ++j) {
    int b = t * 64 + j;
    off[b] = base;
    cur[b] = base;
    base += hist[b];
  }
  if (t == 1023) off[NBUCK] = base;
}

__global__ __launch_bounds__(256) void k4_scatter(const u64* __restrict__ keys,
    int* __restrict__ cur, u64* __restrict__ membuf)
{
  int i = blockIdx.x * 256 + threadIdx.x;
  if (i >= NA) return;
  u64 k = keys[i];
  int p = atomicAdd(&cur[(unsigned)(k >> 46)], 1);
  membuf[p] = k;
}

__global__ __launch_bounds__(256) void k4_rank(const u64* __restrict__ keys,
    const int* __restrict__ off, const u64* __restrict__ membuf,
    const float4* __restrict__ boxes, float4* __restrict__ cand,
    float* __restrict__ areas)
{
  int i = blockIdx.x * 256 + threadIdx.x;
  if (i >= NA) return;
  u64 my = keys[i];
  unsigned b = (unsigned)(my >> 46);
  int lo = off[b], hi = off[b + 1];
  int r = NA - hi;            // all keys in strictly-higher buckets
  for (int p = lo; p < hi; ++p) r += (membuf[p] > my) ? 1 : 0;
  if (r < TOPN) {
    unsigned idx = 0xFFFFFFFFu - (unsigned)my;
    float4 bx = boxes[idx];
    cand[r] = bx;
    areas[r] = (bx.z - bx.x) * (bx.w - bx.y);
  }
}

// ---------------- K5: IoU > 0.7 bit matrix; one thread per 64-bit word ----------------
__global__ __launch_bounds__(256) void k5_iou(const float4* __restrict__ cand,
    const float* __restrict__ areas, u64* __restrict__ rowbuf)
{
  __shared__ float4 bj[64];
  __shared__ float aj[64];
  int jw = blockIdx.x;
  int i = blockIdx.y * 256 + threadIdx.x;
  if (threadIdx.x < 64) {
    int j = jw * 64 + threadIdx.x;
    bj[threadIdx.x] = (j < TOPN) ? cand[j] : make_float4(0.f, 0.f, 0.f, 0.f);
    aj[threadIdx.x] = (j < TOPN) ? areas[j] : 0.f;
  }
  __syncthreads();
  if (i >= TOPN) return;
  u64 word = 0ull;
  if (jw * 64 + 63 > i) {
    float4 bi = cand[i];
    float ai = areas[i];
#pragma unroll 8
    for (int b = 0; b < 64; ++b) {
      float4 bb = bj[b];
      float lx = fmaxf(bi.x, bb.x), ly = fmaxf(bi.y, bb.y);
      float rx = fminf(bi.z, bb.z), ry = fminf(bi.w, bb.w);
      float ww = fmaxf(rx - lx, 0.f), hh = fmaxf(ry - ly, 0.f);
      float inter = ww * hh;
      float iou = inter / (ai + aj[b] - inter + 1e-9f);
      int j = jw * 64 + b;
      if (iou > 0.7f && j > i && j < TOPN) word |= 1ull << b;
    }
  }
  rowbuf[(size_t)i * 96 + jw] = word;
}

// ---------------- K6: greedy NMS scan, prefetched + early-exit (single block) ----------------
__global__ __launch_bounds__(256) void k6_scan(const u64* __restrict__ rowbuf,
    const float4* __restrict__ cand, float4* __restrict__ rois)
{
  __shared__ u64 stage[64 * 97];
  __shared__ u64 sup[94];
  __shared__ int prefS[94];
  __shared__ int baseU_sh;
  int tid = threadIdx.x;
  if (tid < 94) sup[tid] = 0ull;
  if (tid == 0) baseU_sh = 0;

  u64 pre[24];
#pragma unroll
  for (int j = 0; j < 24; ++j) {
    int o = j * 256 + tid;
    int b = o / 94, w = o - b * 94;
    pre[j] = (o < 6016) ? rowbuf[(size_t)b * 96 + w] : 0ull;
  }
  __syncthreads();

  for (int c = 0; c < 94; ++c) {
#pragma unroll
    for (int j = 0; j < 24; ++j) {
      int o = j * 256 + tid;
      int b = o / 94, w = o - b * 94;
      if (o < 6016) stage[b * 97 + w] = pre[j];
    }
    __syncthreads();
    if (c + 1 < 94) {
#pragma unroll
      for (int j = 0; j < 24; ++j) {
        int o = j * 256 + tid;
        int b = o / 94, w = o - b * 94;
        pre[j] = (o < 6016) ? rowbuf[((size_t)(c + 1) * 64 + b) * 96 + w] : 0ull;
      }
    }
    u64 valid = (c == 93) ? ((1ull << 48) - 1ull) : ~0ull;
    u64 sup_c = sup[c];
    u64 live0 = ~sup_c & valid;
    u64 rw = stage[(tid & 63) * 97 + c];
    u64 live = live0, keep = 0ull;
    while (live) {
      int b = __builtin_ctzll(live);
      keep |= 1ull << b;
      u64 rb = (u64)__shfl((long long)rw, b);
      live &= ~rb;
      live &= ~(1ull << b);
    }
    int baseU = baseU_sh;
    if (tid < 64 && ((keep >> tid) & 1ull)) {
      u64 below = (tid == 0) ? 0ull : (keep & ((1ull << tid) - 1ull));
      int pos = baseU + __popcll(below);
      if (pos < NKEEP) rois[pos] = cand[c * 64 + tid];
    }
    __syncthreads();
    if (tid == 0) baseU_sh = baseU + __popcll(keep);
    if (tid == 64) sup[c] = sup_c | (live0 & ~keep);
    for (int w = c + 1 + tid; w < 94; w += 256) {
      u64 a = sup[w];
#pragma unroll 16
      for (int b = 0; b < 64; ++b)
        if ((keep >> b) & 1ull) a |= stage[b * 97 + w];
      sup[w] = a;
    }
    __syncthreads();
    if (baseU_sh >= NKEEP) break;
  }

  int totU = baseU_sh;
  if (totU < NKEEP) {
    if (tid == 0) {
      int s = 0;
      for (int w = 0; w < 94; ++w) { prefS[w] = s; s += __popcll(sup[w]); }
    }
    __syncthreads();
    for (int i = tid; i < TOPN; i += 256) {
      int w = i >> 6, b = i & 63;
      u64 sw = sup[w];
      if ((sw >> b) & 1ull) {
        u64 below = (b == 0) ? 0ull : (sw & ((1ull << b) - 1ull));
        int pos = totU + prefS[w] + __popcll(below);
        if (pos < NKEEP) rois[pos] = cand[i];
      }
    }
  }
}

// ---------------- K7: roi_align -> pool bf16 [roi][c*49+py*7+px] ----------------
__global__ __launch_bounds__(256) void k7_roi(const float4* __restrict__ rois,
    const float* __restrict__ feat_t, unsigned short* __restrict__ pool_bf)
{
  int r = blockIdx.x;
  int py = blockIdx.y / 7, px = blockIdx.y - (blockIdx.y / 7) * 7;
  int c = threadIdx.x;
  float4 box = rois[r];
  float x1 = box.x * 0.0625f, y1 = box.y * 0.0625f;
  float x2 = box.z * 0.0625f, y2 = box.w * 0.0625f;
  float acc0 = 0.f, acc1 = 0.f;
#pragma unroll
  for (int sy = 0; sy < 2; ++sy) {
#pragma unroll
    for (int sx = 0; sx < 2; ++sx) {
      float offx = ((float)(2 * px + sx) + 0.5f) * 0.5f;
      float offy = ((float)(2 * py + sy) + 0.5f) * 0.5f;
      float xs = x1 + (offx * (x2 - x1)) / 7.f;
      float ys = y1 + (offy * (y2 - y1)) / 7.f;
      float x0f = floorf(xs), y0f = floorf(ys);
      float lx = xs - x0f, ly = ys - y0f;
      int x0i = (int)fminf(fmaxf(x0f, 0.f), 49.f);
      int x1i = (int)fminf(fmaxf(x0f + 1.f, 0.f), 49.f);
      int y0i = (int)fminf(fmaxf(y0f, 0.f), 49.f);
      int y1i = (int)fminf(fmaxf(y0f + 1.f, 0.f), 49.f);
      const float* f00 = feat_t + (size_t)(y0i * 50 + x0i) * 512;
      const float* f01 = feat_t + (size_t)(y0i * 50 + x1i) * 512;
      const float* f10 = feat_t + (size_t)(y1i * 50 + x0i) * 512;
      const float* f11 = feat_t + (size_t)(y1i * 50 + x1i) * 512;
      float w00 = (1.f - ly) * (1.f - lx), w01 = (1.f - ly) * lx;
      float w10 = ly * (1.f - lx),          w11 = ly * lx;
      acc0 += w00 * f00[c] + w01 * f01[c] + w10 * f10[c] + w11 * f11[c];
      acc1 += w00 * f00[c + 256] + w01 * f01[c + 256] + w10 * f10[c + 256] + w11 * f11[c + 256];
    }
  }
  pool_bf[(size_t)r * 25088 + c * 49 + py * 7 + px] = f2bf(acc0 * 0.25f);
  pool_bf[(size_t)r * 25088 + (c + 256) * 49 + py * 7 + px] = f2bf(acc1 * 0.25f);
}

// ---------------- K8: fc7 GEMM bf16 MFMA, split-K ----------------
__global__ __launch_bounds__(512) void k8_gemm(const unsigned short* __restrict__ A,
    const float* __restrict__ W, float* __restrict__ partial, int klen)
{
  __shared__ __align__(16) unsigned short As[8 * 320 * 8];
  __shared__ __align__(16) unsigned short Bs[8 * 128 * 8];
  int tid = threadIdx.x;
  int lane = tid & 63, wv = tid >> 6;
  int wm = wv & 1, wn = wv >> 1;
  int n0 = blockIdx.x * 128;
  int kbase = blockIdx.y * klen;
  f32x4 acc[10][2];
#pragma unroll
  for (int i = 0; i < 10; ++i)
#pragma unroll
    for (int j = 0; j < 2; ++j) acc[i][j] = (f32x4){0.f, 0.f, 0.f, 0.f};

  for (int kt = 0; kt < klen; kt += 64) {
    int k0 = kbase + kt;
#pragma unroll
    for (int j = 0; j < 5; ++j) {
      int o = j * 512 + tid;
      int g = o / 320, m = o - g * 320;
      ((ushort8*)As)[o] = *(const ushort8*)(A + (size_t)m * 25088 + k0 + g * 8);
    }
#pragma unroll
    for (int j = 0; j < 4; ++j) {
      int fq = j * 512 + tid;
      int n = fq >> 4, kq = fq & 15;
      float4 v = *(const float4*)(W + (size_t)(n0 + n) * 25088 + k0 + kq * 4);
      u64 pk = (u64)f2bf(v.x) | ((u64)f2bf(v.y) << 16)
             | ((u64)f2bf(v.z) << 32) | ((u64)f2bf(v.w) << 48);
      int g = kq >> 1;
      *(u64*)&Bs[(g * 128 + n) * 8 + (kq & 1) * 4] = pk;
    }
    __syncthreads();
#pragma unroll
    for (int kk = 0; kk < 2; ++kk) {
      int g = kk * 4 + (lane >> 4);
      short8 b0 = ((const short8*)Bs)[g * 128 + wn * 32 + (lane & 15)];
      short8 b1 = ((const short8*)Bs)[g * 128 + wn * 32 + 16 + (lane & 15)];
#pragma unroll
      for (int fm = 0; fm < 10; ++fm) {
        short8 a = ((const short8*)As)[g * 320 + wm * 160 + fm * 16 + (lane & 15)];
        acc[fm][0] = __builtin_amdgcn_mfma_f32_16x16x32_bf16(a, b0, acc[fm][0], 0, 0, 0);
        acc[fm][1] = __builtin_amdgcn_mfma_f32_16x16x32_bf16(a, b1, acc[fm][1], 0, 0, 0);
      }
    }
    __syncthreads();
  }
  float* P = partial + (size_t)(blockIdx.y * 32 + blockIdx.x) * (320 * 128);
#pragma unroll
  for (int fm = 0; fm < 10; ++fm)
#pragma unroll
    for (int fn = 0; fn < 2; ++fn)
#pragma unroll
      for (int r = 0; r < 4; ++r) {
        int m = wm * 160 + fm * 16 + (lane >> 4) * 4 + r;
        int n = wn * 32 + fn * 16 + (lane & 15);
        P[m * 128 + n] = acc[fm][fn][r];
      }
}

__global__ __launch_bounds__(256) void k8_reduce(const float* __restrict__ partial,
    const float* __restrict__ bias, float* __restrict__ fc7, int KS)
{
  int idx = blockIdx.x * 256 + threadIdx.x;
  if (idx >= 300 * 4096) return;
  int m = idx >> 12, n = idx & 4095;
  int nt = n >> 7, nn = n & 127;
  float s = 0.f;
  for (int ks = 0; ks < KS; ++ks)
    s += partial[((size_t)(ks * 32 + nt) * 320 + m) * 128 + nn];
  s += bias[n];
  fc7[idx] = fmaxf(s, 0.f);
}

// ---------------- K9: cls/reg heads ----------------
__global__ __launch_bounds__(128) void k9_head(const float* __restrict__ fc7,
    const float* __restrict__ wc, const float* __restrict__ bc,
    const float* __restrict__ wr, const float* __restrict__ br,
    float* __restrict__ out)
{
  __shared__ float4 fv4[1024];
  int m = blockIdx.x, tid = threadIdx.x;
  const float4* src = (const float4*)(fc7 + (size_t)m * 4096);
  for (int i = tid; i < 1024; i += 128) fv4[i] = src[i];
  __syncthreads();
  if (tid < 105) {
    const float* w; float b;
    if (tid < 21) { w = wc + tid * 4096; b = bc[tid]; }
    else          { w = wr + (tid - 21) * 4096; b = br[tid - 21]; }
    const float4* w4 = (const float4*)w;
    float s = 0.f;
#pragma unroll 4
    for (int q = 0; q < 1024; ++q) {
      float4 a = fv4[q], ww = w4[q];
      s += a.x * ww.x + a.y * ww.y + a.z * ww.z + a.w * ww.w;
    }
    s += b;
    if (tid < 21) out[m * 21 + tid] = s;
    else          out[6300 + m * 84 + (tid - 21)] = s;
  }
}

extern "C" void kernel_launch(void* const* d_in, const int* in_sizes, int n_in,
                              void* d_out, int out_size, void* d_ws, size_t ws_size,
                              hipStream_t stream)
{
  (void)in_sizes; (void)n_in; (void)out_size;
  const float* img    = (const float*)d_in[0];
  const float* w_feat = (const float*)d_in[1];
  const float* b_feat = (const float*)d_in[2];
  const float* w_rpn  = (const float*)d_in[3];
  const float* b_rpn  = (const float*)d_in[4];
  const float* w_score= (const float*)d_in[5];
  const float* b_score= (const float*)d_in[6];
  const float* w_delta= (const float*)d_in[7];
  const float* b_delta= (const float*)d_in[8];
  const float* w_fc7  = (const float*)d_in[9];
  const float* b_fc7  = (const float*)d_in[10];
  const float* w_cls  = (const float*)d_in[11];
  const float* b_cls  = (const float*)d_in[12];
  const float* w_reg  = (const float*)d_in[13];
  const float* b_reg  = (const float*)d_in[14];
  float* out = (float*)d_out;

  char* ws = (char*)d_ws;
  size_t off = 0;
  auto alloc = [&](size_t bytes) -> void* {
    void* p = ws + off;
    off = (off + bytes + 511) & ~(size_t)511;
    return p;
  };
  float* feat    = (float*)alloc(5120000);
  float* feat_t  = (float*)alloc(5120000);
  float* h_t     = (float*)alloc(5120000);
  float4* boxes  = (float4*)alloc((size_t)NA * 16);
  u64* keys      = (u64*)alloc((size_t)NA * 8);
  int* hist      = (int*)alloc((size_t)NBUCK * 4);
  int* boff      = (int*)alloc((size_t)(NBUCK + 1) * 4);
  int* bcur      = (int*)alloc((size_t)NBUCK * 4);
  u64* membuf    = (u64*)alloc((size_t)NA * 8);
  float4* cand   = (float4*)alloc((size_t)TOPN * 16);
  float* areas   = (float*)alloc((size_t)TOPN * 4);
  u64* rowbuf    = (u64*)alloc((size_t)TOPN * 96 * 8);
  float4* rois   = (float4*)alloc(NKEEP * 16);
  unsigned short* pool_bf = (unsigned short*)alloc((size_t)320 * 25088 * 2);
  float* fc7     = (float*)alloc((size_t)300 * 4096 * 4);

  // shared split-K partial buffer (k1, k2, k8 reuse it sequentially)
  size_t avail = (ws_size > off) ? (ws_size - off) : 0;
  float* P_sh = (float*)(ws + off);
  int KS1 = 8, KS2 = 16, KS8 = 8;
  while (KS2 > 1 && (size_t)KS2 * 80 * 16384 * 4 > avail) KS2 >>= 1;
  while (KS1 > 1 && (size_t)KS1 * 80 * 16384 * 4 > avail) KS1 >>= 1;
  while (KS8 > 1 && (size_t)KS8 * 32 * 320 * 128 * 4 > avail) KS8 >>= 1;
  int klen1 = 768 / KS1, klen2 = 4608 / KS2, klen8 = 25088 / KS8;

  kgemm_f32<0><<<dim3(20, 4, KS1), 256, 0, stream>>>(img, w_feat, P_sh, klen1, 768);
  kred1<<<(NPOS * 512 + 255) / 256, 256, 0, stream>>>(P_sh, b_feat, feat, feat_t, KS1);
  kgemm_f32<1><<<dim3(20, 4, KS2), 256, 0, stream>>>(feat, w_rpn, P_sh, klen2, 4608);
  kred2<<<(NPOS * 512 + 255) / 256, 256, 0, stream>>>(P_sh, b_rpn, h_t, KS2);
  k3_head<<<2500, 64, 0, stream>>>(h_t, w_score, b_score, w_delta, b_delta, boxes, keys);
  hipMemsetAsync(hist, 0, (size_t)NBUCK * 4, stream);
  k4_hist   <<<88, 256, 0, stream>>>(keys, hist);
  k4_scan   <<<1, 1024, 0, stream>>>(hist, boff, bcur);
  k4_scatter<<<88, 256, 0, stream>>>(keys, bcur, membuf);
  k4_rank   <<<88, 256, 0, stream>>>(keys, boff, membuf, boxes, cand, areas);
  k5_iou    <<<dim3(94, 24), 256, 0, stream>>>(cand, areas, rowbuf);
  k6_scan   <<<1, 256, 0, stream>>>(rowbuf, cand, rois);
  hipMemsetAsync((void*)pool_bf, 0, (size_t)320 * 25088 * 2, stream);
  k7_roi    <<<dim3(300, 49), 256, 0, stream>>>(rois, feat_t, pool_bf);
  k8_gemm   <<<dim3(32, KS8), 512, 0, stream>>>(pool_bf, w_fc7, P_sh, klen8);
  k8_reduce <<<(300 * 4096 + 255) / 256, 256, 0, stream>>>(P_sh, b_fc7, fc7, KS8);
  k9_head   <<<300, 128, 0, stream>>>(fc7, w_cls, b_cls, w_reg, b_reg, out);
}